// Round 3
// baseline (10221.467 us; speedup 1.0000x reference)
//
#include <hip/hip_runtime.h>

// GRU rollout decoder, MI355X. bf16x3 (hi/lo split) MFMA GEMMs, fp32 accumulate.
// Per step: gru_cell (gates+h_new fused) + gru_head (y -> out, next x).
// R2: cell re-tiled BM=32/BN=64 -> BM=64/BN=32 (256 blocks kept): per-step L2
// traffic 291->205 MB (W-dup halves, cell is L2-request-rate bound ~60B/cyc/CU).

typedef __attribute__((ext_vector_type(8))) short bf16x8;
typedef __attribute__((ext_vector_type(4))) float f32x4;
typedef __attribute__((ext_vector_type(8))) unsigned short us8;

#define I_ 256
#define H_ 1024
#define B_ 512
#define L_ 256

#define MFMA(A, Bm, C) C = __builtin_amdgcn_mfma_f32_16x16x32_bf16(A, Bm, C, 0, 0, 0)

__device__ __forceinline__ unsigned short f2bf(float f) {
  unsigned u = __float_as_uint(f);
  u += 0x7FFFu + ((u >> 16) & 1u);   // round-to-nearest-even
  return (unsigned short)(u >> 16);
}
__device__ __forceinline__ float bf2f(unsigned short s) {
  return __uint_as_float(((unsigned)s) << 16);
}

// ---------------------------------------------------------------------------
// prep: split W_hh, W_ih, W_head, context into bf16 hi/lo pairs
// ---------------------------------------------------------------------------
__global__ void gru_prep(const float* __restrict__ whh, const float* __restrict__ wih,
                         const float* __restrict__ whd, const float* __restrict__ ctx,
                         unsigned short* __restrict__ whh_h, unsigned short* __restrict__ whh_l,
                         unsigned short* __restrict__ wih_h, unsigned short* __restrict__ wih_l,
                         unsigned short* __restrict__ whd_h, unsigned short* __restrict__ whd_l,
                         unsigned short* __restrict__ hh, unsigned short* __restrict__ hl) {
  const int NWHH = 3 * H_ * H_;
  const int NWIH = 3 * H_ * I_;
  const int NWHD = I_ * H_;
  const int NCTX = B_ * H_;
  const int tot = NWHH + NWIH + NWHD + NCTX;
  for (int idx = blockIdx.x * blockDim.x + threadIdx.x; idx < tot;
       idx += gridDim.x * blockDim.x) {
    const float* src; unsigned short* dh; unsigned short* dl; int off;
    if (idx < NWHH) { src = whh; dh = whh_h; dl = whh_l; off = idx; }
    else if (idx < NWHH + NWIH) { src = wih; dh = wih_h; dl = wih_l; off = idx - NWHH; }
    else if (idx < NWHH + NWIH + NWHD) { src = whd; dh = whd_h; dl = whd_l; off = idx - NWHH - NWIH; }
    else { src = ctx; dh = hh; dl = hl; off = idx - NWHH - NWIH - NWHD; }
    float v = src[off];
    unsigned short h = f2bf(v);
    dh[off] = h;
    dl[off] = f2bf(v - bf2f(h));
  }
}

// ---------------------------------------------------------------------------
// gru_cell: one recurrence step.  BM=64 batch rows x BN=32 h-cols per block.
// 4 waves as 2x2: wr (row half, 32 rows = 2 frags) x wc (col half, 16 cols).
// Acc per wave: accR/accZ (x+h combined), accGin (x), accGhn (h) -- 8 f32x4.
// K phases: 32 over h (K=1024) then 8 over x (K=256) unless t==0.
// bf16x3: dot = Ah@Wh + Ah@Wl + Al@Wh.
// LDS double-buffered, one barrier per phase, pad-40 ushort rows (<=2-way banks).
// ---------------------------------------------------------------------------
__global__ __launch_bounds__(256) void gru_cell(
    const unsigned short* __restrict__ h_h, const unsigned short* __restrict__ h_l,
    const unsigned short* __restrict__ x_h, const unsigned short* __restrict__ x_l,
    const unsigned short* __restrict__ whh_h, const unsigned short* __restrict__ whh_l,
    const unsigned short* __restrict__ wih_h, const unsigned short* __restrict__ wih_l,
    const float* __restrict__ b_ih, const float* __restrict__ b_hh,
    unsigned short* __restrict__ ho_h, unsigned short* __restrict__ ho_l,
    int use_x) {
  __shared__ __align__(16) unsigned short A_lds[2][2][64][40];  // [buf][hi/lo][row][k+pad]
  __shared__ __align__(16) unsigned short W_lds[2][2][96][40];  // [buf][hi/lo][g*32+j][k+pad]

  const int tid = threadIdx.x;
  const int bid = blockIdx.x;
  // XCD-affinity: bids == x (mod 8) land on XCD x; give XCD x jt in {4x..4x+3}
  // -> W working set per XCD ~1.9MB < 4MB L2.
  const int xcd = bid & 7;
  const int q = bid >> 3;                 // 0..31
  const int jt = xcd * 4 + (q & 3);       // 0..31  h-col tile (32 cols)
  const int bt = q >> 2;                  // 0..7   batch tile (64 rows)

  const int w = tid >> 6;                 // wave 0..3
  const int wr = w >> 1;                  // row half (32 rows)
  const int wc = w & 1;                   // col half (16 cols)
  const int lane = tid & 63;
  const int m = lane & 15;                // frag row/col within 16
  const int ko = (lane >> 4) << 3;        // k offset: 0,8,16,24
  const int wj = wc * 16 + m;             // W_lds row within gate block (0..31)

  f32x4 accR[2] = {}; f32x4 accZ[2] = {}; f32x4 accGin[2] = {}; f32x4 accGhn[2] = {};
  us8 rg[5];  // staging: 2 A slots + 3 W slots per thread per phase (1280 slots)

  auto load_phase = [&](int p) {
    const unsigned short *Ah_s, *Al_s, *Wh_s, *Wl_s;
    int kb, ldA, ldW;
    if (p < 32) { Ah_s = h_h; Al_s = h_l; Wh_s = whh_h; Wl_s = whh_l; kb = p << 5; ldA = H_; ldW = H_; }
    else        { Ah_s = x_h; Al_s = x_l; Wh_s = wih_h; Wl_s = wih_l; kb = (p - 32) << 5; ldA = I_; ldW = I_; }
#pragma unroll
    for (int i = 0; i < 2; ++i) {  // A: 2hl x 64 rows x 4 slots = 512
      int t2 = i * 256 + tid;
      int hl2 = t2 >> 8, rem = t2 & 255;
      int rr = rem >> 2, ss = rem & 3;
      const unsigned short* s = hl2 ? Al_s : Ah_s;
      rg[i] = *(const us8*)&s[(bt * 64 + rr) * ldA + kb + ss * 8];
    }
#pragma unroll
    for (int i = 2; i < 5; ++i) {  // W: 2hl x 96 rows x 4 slots = 768
      int t2 = (i - 2) * 256 + tid;               // 0..767
      int hl2 = (t2 >= 384) ? 1 : 0;
      int rem = t2 - 384 * hl2;                   // 0..383
      int row = rem >> 2, ss = rem & 3;           // row = g*32+jr
      int g = row >> 5, jr = row & 31;
      const unsigned short* s = hl2 ? Wl_s : Wh_s;
      rg[i] = *(const us8*)&s[(g * H_ + jt * 32 + jr) * ldW + kb + ss * 8];
    }
  };

  auto write_phase = [&](int nb) {
#pragma unroll
    for (int i = 0; i < 2; ++i) {
      int t2 = i * 256 + tid;
      int hl2 = t2 >> 8, rem = t2 & 255;
      int rr = rem >> 2, ss = rem & 3;
      *(us8*)&A_lds[nb][hl2][rr][ss * 8] = rg[i];
    }
#pragma unroll
    for (int i = 2; i < 5; ++i) {
      int t2 = (i - 2) * 256 + tid;
      int hl2 = (t2 >= 384) ? 1 : 0;
      int rem = t2 - 384 * hl2;
      int row = rem >> 2, ss = rem & 3;
      *(us8*)&W_lds[nb][hl2][row][ss * 8] = rg[i];
    }
  };

  auto compute_phase = [&](int cb, f32x4 (&accN)[2]) {
    bf16x8 ah0 = *(const bf16x8*)&A_lds[cb][0][wr * 32 + m][ko];
    bf16x8 ah1 = *(const bf16x8*)&A_lds[cb][0][wr * 32 + 16 + m][ko];
    bf16x8 al0 = *(const bf16x8*)&A_lds[cb][1][wr * 32 + m][ko];
    bf16x8 al1 = *(const bf16x8*)&A_lds[cb][1][wr * 32 + 16 + m][ko];
    bf16x8 wrh = *(const bf16x8*)&W_lds[cb][0][wj][ko];
    bf16x8 wrl = *(const bf16x8*)&W_lds[cb][1][wj][ko];
    bf16x8 wzh = *(const bf16x8*)&W_lds[cb][0][wj + 32][ko];
    bf16x8 wzl = *(const bf16x8*)&W_lds[cb][1][wj + 32][ko];
    bf16x8 wnh = *(const bf16x8*)&W_lds[cb][0][wj + 64][ko];
    bf16x8 wnl = *(const bf16x8*)&W_lds[cb][1][wj + 64][ko];
    MFMA(ah0, wrh, accR[0]); MFMA(ah0, wrl, accR[0]); MFMA(al0, wrh, accR[0]);
    MFMA(ah1, wrh, accR[1]); MFMA(ah1, wrl, accR[1]); MFMA(al1, wrh, accR[1]);
    MFMA(ah0, wzh, accZ[0]); MFMA(ah0, wzl, accZ[0]); MFMA(al0, wzh, accZ[0]);
    MFMA(ah1, wzh, accZ[1]); MFMA(ah1, wzl, accZ[1]); MFMA(al1, wzh, accZ[1]);
    MFMA(ah0, wnh, accN[0]); MFMA(ah0, wnl, accN[0]); MFMA(al0, wnh, accN[0]);
    MFMA(ah1, wnh, accN[1]); MFMA(ah1, wnl, accN[1]); MFMA(al1, wnh, accN[1]);
  };

  // pipeline: compute phase p from buf p&1; write phase p+1 into buf (p+1)&1.
  load_phase(0);
  write_phase(0);
  load_phase(1);
  const int NP = use_x ? 40 : 32;
  for (int p = 0; p < NP; ++p) {
    __syncthreads();
    write_phase((p + 1) & 1);
    int pl = (p + 2 < NP) ? (p + 2) : (NP - 1);
    load_phase(pl);
    if (p < 32) compute_phase(p & 1, accGhn);
    else        compute_phase(p & 1, accGin);
  }

  // epilogue: gates + h_new.  D layout: col = lane&15, row = (lane>>4)*4 + reg.
  const int j = jt * 32 + wc * 16 + m;
  const float bir = b_ih[j],          bhr = b_hh[j];
  const float biz = b_ih[H_ + j],     bhz = b_hh[H_ + j];
  const float bin = b_ih[2 * H_ + j], bhn = b_hh[2 * H_ + j];
  const int r0 = (lane >> 4) << 2;
#pragma unroll
  for (int bf = 0; bf < 2; ++bf) {
#pragma unroll
    for (int r2 = 0; r2 < 4; ++r2) {
      int b = bt * 64 + wr * 32 + bf * 16 + r0 + r2;
      float gr = accR[bf][r2] + bir + bhr;
      float gz = accZ[bf][r2] + biz + bhz;
      float rr = 1.f / (1.f + __expf(-gr));
      float zz = 1.f / (1.f + __expf(-gz));
      float gn = accGin[bf][r2] + bin + rr * (accGhn[bf][r2] + bhn);
      float nn = tanhf(gn);
      float hold = bf2f(h_h[b * H_ + j]) + bf2f(h_l[b * H_ + j]);
      float hn = (1.f - zz) * nn + zz * hold;
      unsigned short hi = f2bf(hn);
      ho_h[b * H_ + j] = hi;
      ho_l[b * H_ + j] = f2bf(hn - bf2f(hi));
    }
  }
}

// ---------------------------------------------------------------------------
// gru_head: y = h_new @ W_head^T + b_head.  Writes fp32 ys[t] and bf16 hi/lo x.
// 256 blocks: 32 b-tiles (16 rows) x 8 i-tiles (32 cols); 128 threads = 2 waves,
// wave w owns i-cols w*16..w*16+15, full K=1024.  bid&7 = it -> XCD affinity.
// ---------------------------------------------------------------------------
__global__ __launch_bounds__(128) void gru_head(
    const unsigned short* __restrict__ hs_h, const unsigned short* __restrict__ hs_l,
    const unsigned short* __restrict__ whd_h, const unsigned short* __restrict__ whd_l,
    const float* __restrict__ b_head,
    float* __restrict__ out,
    unsigned short* __restrict__ xo_h, unsigned short* __restrict__ xo_l) {
  __shared__ __align__(16) unsigned short A_lds[2][2][16][40];
  __shared__ __align__(16) unsigned short W_lds[2][2][32][40];

  const int tid = threadIdx.x;
  const int bid = blockIdx.x;
  const int it = bid & 7;    // i tile, 32 cols  (maps to XCD bid%8)
  const int bt = bid >> 3;   // batch tile, 16 rows
  const int w = tid >> 6, lane = tid & 63, m = lane & 15;
  const int ko = (lane >> 4) << 3;

  f32x4 acc = {};
  us8 rg[3];

  auto load_ph = [&](int p) {
    int kb = p << 5;
    {  // A region: 2hl x 16 rows x 4 slots = 128, 1/thread
      int hl2 = tid >> 6, rr = (tid >> 2) & 15, ss = tid & 3;
      const unsigned short* s = hl2 ? hs_l : hs_h;
      rg[0] = *(const us8*)&s[(bt * 16 + rr) * H_ + kb + ss * 8];
    }
#pragma unroll
    for (int i = 1; i < 3; ++i) {  // W region: 2hl x 32 rows x 4 slots = 256
      int t2 = (i - 1) * 128 + tid;    // 0..255
      int hl2 = t2 >> 7, rem = t2 & 127;
      int ir = rem >> 2, ss = rem & 3;
      const unsigned short* s = hl2 ? whd_l : whd_h;
      rg[i] = *(const us8*)&s[(it * 32 + ir) * H_ + kb + ss * 8];
    }
  };

  auto write_ph = [&](int nb) {
    {
      int hl2 = tid >> 6, rr = (tid >> 2) & 15, ss = tid & 3;
      *(us8*)&A_lds[nb][hl2][rr][ss * 8] = rg[0];
    }
#pragma unroll
    for (int i = 1; i < 3; ++i) {
      int t2 = (i - 1) * 128 + tid;
      int hl2 = t2 >> 7, rem = t2 & 127;
      int ir = rem >> 2, ss = rem & 3;
      *(us8*)&W_lds[nb][hl2][ir][ss * 8] = rg[i];
    }
  };

  auto comp = [&](int cb) {
    bf16x8 ah = *(const bf16x8*)&A_lds[cb][0][m][ko];
    bf16x8 al = *(const bf16x8*)&A_lds[cb][1][m][ko];
    bf16x8 wh = *(const bf16x8*)&W_lds[cb][0][w * 16 + m][ko];
    bf16x8 wl = *(const bf16x8*)&W_lds[cb][1][w * 16 + m][ko];
    MFMA(ah, wh, acc); MFMA(ah, wl, acc); MFMA(al, wh, acc);
  };

  load_ph(0);
  write_ph(0);
  load_ph(1);
  const int NP = 32;
  for (int p = 0; p < NP; ++p) {
    __syncthreads();
    write_ph((p + 1) & 1);
    int pl = (p + 2 < NP) ? (p + 2) : (NP - 1);
    load_ph(pl);
    comp(p & 1);
  }

  const int i = it * 32 + w * 16 + m;
  const float bh = b_head[i];
  const int r0 = (lane >> 4) << 2;
#pragma unroll
  for (int r2 = 0; r2 < 4; ++r2) {
    int b = bt * 16 + r0 + r2;
    float y = acc[r2] + bh;
    out[b * I_ + i] = y;
    unsigned short hi = f2bf(y);
    xo_h[b * I_ + i] = hi;
    xo_l[b * I_ + i] = f2bf(y - bf2f(hi));
  }
}

// ---------------------------------------------------------------------------
extern "C" void kernel_launch(void* const* d_in, const int* in_sizes, int n_in,
                              void* d_out, int out_size, void* d_ws, size_t ws_size,
                              hipStream_t stream) {
  (void)in_sizes; (void)n_in; (void)out_size; (void)ws_size;
  const float* ctx    = (const float*)d_in[0];
  // d_in[1] = length (scalar, fixed 256)
  const float* W_ih   = (const float*)d_in[2];
  const float* W_hh   = (const float*)d_in[3];
  const float* b_ih   = (const float*)d_in[4];
  const float* b_hh   = (const float*)d_in[5];
  const float* W_head = (const float*)d_in[6];
  const float* b_head = (const float*)d_in[7];
  float* out = (float*)d_out;

  char* p = (char*)d_ws;
  unsigned short* whh_h = (unsigned short*)p; p += 6291456;
  unsigned short* whh_l = (unsigned short*)p; p += 6291456;
  unsigned short* wih_h = (unsigned short*)p; p += 1572864;
  unsigned short* wih_l = (unsigned short*)p; p += 1572864;
  unsigned short* whd_h = (unsigned short*)p; p += 524288;
  unsigned short* whd_l = (unsigned short*)p; p += 524288;
  unsigned short* hh[2]; unsigned short* hl[2];
  hh[0] = (unsigned short*)p; p += 1048576;
  hl[0] = (unsigned short*)p; p += 1048576;
  hh[1] = (unsigned short*)p; p += 1048576;
  hl[1] = (unsigned short*)p; p += 1048576;
  unsigned short* xh = (unsigned short*)p; p += 262144;
  unsigned short* xl = (unsigned short*)p; p += 262144;
  // total ws used: 21,495,808 bytes

  gru_prep<<<2048, 256, 0, stream>>>(W_hh, W_ih, W_head, ctx,
                                     whh_h, whh_l, wih_h, wih_l, whd_h, whd_l,
                                     hh[0], hl[0]);

  for (int t = 0; t < L_; ++t) {
    const int src = t & 1, dst = src ^ 1;
    gru_cell<<<256, 256, 0, stream>>>(hh[src], hl[src], xh, xl,
                                      whh_h, whh_l, wih_h, wih_l,
                                      b_ih, b_hh, hh[dst], hl[dst], t > 0 ? 1 : 0);
    gru_head<<<256, 128, 0, stream>>>(hh[dst], hl[dst], whd_h, whd_l, b_head,
                                      out + (size_t)t * B_ * I_, xh, xl);
  }
}

// Round 7
// 7382.734 us; speedup vs baseline: 1.3845x; 1.3845x over previous
//
#include <hip/hip_runtime.h>

// GRU rollout decoder, MI355X. bf16x3 (hi/lo split) MFMA GEMMs, fp32 accumulate.
// R3..R6: latency-tolerance restructure (vs measured 10.2ms @ 4-wave/K32 baseline):
//  - cell: 256thr/4waves -> 512thr/8waves (2 waves/SIMD TLP), K-step 32->64 (20 phases)
//  - head: K-step 32->128 (8 phases)
//  - s_setprio(1) around MFMA clusters
// Cell tile BM=64 x BN=32 (x3 gates), 256 blocks; head 16x32, 256 blocks.

typedef __attribute__((ext_vector_type(8))) short bf16x8;
typedef __attribute__((ext_vector_type(4))) float f32x4;
typedef __attribute__((ext_vector_type(8))) unsigned short us8;

#define I_ 256
#define H_ 1024
#define B_ 512
#define L_ 256

#define MFMA(A, Bm, C) C = __builtin_amdgcn_mfma_f32_16x16x32_bf16(A, Bm, C, 0, 0, 0)

__device__ __forceinline__ unsigned short f2bf(float f) {
  unsigned u = __float_as_uint(f);
  u += 0x7FFFu + ((u >> 16) & 1u);   // round-to-nearest-even
  return (unsigned short)(u >> 16);
}
__device__ __forceinline__ float bf2f(unsigned short s) {
  return __uint_as_float(((unsigned)s) << 16);
}

// ---------------------------------------------------------------------------
// prep: split W_hh, W_ih, W_head, context into bf16 hi/lo pairs
// ---------------------------------------------------------------------------
__global__ void gru_prep(const float* __restrict__ whh, const float* __restrict__ wih,
                         const float* __restrict__ whd, const float* __restrict__ ctx,
                         unsigned short* __restrict__ whh_h, unsigned short* __restrict__ whh_l,
                         unsigned short* __restrict__ wih_h, unsigned short* __restrict__ wih_l,
                         unsigned short* __restrict__ whd_h, unsigned short* __restrict__ whd_l,
                         unsigned short* __restrict__ hh, unsigned short* __restrict__ hl) {
  const int NWHH = 3 * H_ * H_;
  const int NWIH = 3 * H_ * I_;
  const int NWHD = I_ * H_;
  const int NCTX = B_ * H_;
  const int tot = NWHH + NWIH + NWHD + NCTX;
  for (int idx = blockIdx.x * blockDim.x + threadIdx.x; idx < tot;
       idx += gridDim.x * blockDim.x) {
    const float* src; unsigned short* dh; unsigned short* dl; int off;
    if (idx < NWHH) { src = whh; dh = whh_h; dl = whh_l; off = idx; }
    else if (idx < NWHH + NWIH) { src = wih; dh = wih_h; dl = wih_l; off = idx - NWHH; }
    else if (idx < NWHH + NWIH + NWHD) { src = whd; dh = whd_h; dl = whd_l; off = idx - NWHH - NWIH; }
    else { src = ctx; dh = hh; dl = hl; off = idx - NWHH - NWIH - NWHD; }
    float v = src[off];
    unsigned short h = f2bf(v);
    dh[off] = h;
    dl[off] = f2bf(v - bf2f(h));
  }
}

// ---------------------------------------------------------------------------
// gru_cell: one recurrence step.  BM=64 batch rows x BN=32 h-cols per block.
// 512 threads = 8 waves as 4x2: wr (16-row frag) x wc (16-col half).
// Acc per wave: accR/accZ (x+h combined), accGin (x), accGhn (h) -- 4 f32x4.
// K-step 64: 16 phases over h (K=1024) then 4 over x (K=256) unless t==0.
// bf16x3: dot = Ah@Wh + Ah@Wl + Al@Wh.
// LDS double-buffered (90KB), one barrier per phase, pad-72 rows (2-way banks).
// ---------------------------------------------------------------------------
__global__ __launch_bounds__(512) void gru_cell(
    const unsigned short* __restrict__ h_h, const unsigned short* __restrict__ h_l,
    const unsigned short* __restrict__ x_h, const unsigned short* __restrict__ x_l,
    const unsigned short* __restrict__ whh_h, const unsigned short* __restrict__ whh_l,
    const unsigned short* __restrict__ wih_h, const unsigned short* __restrict__ wih_l,
    const float* __restrict__ b_ih, const float* __restrict__ b_hh,
    unsigned short* __restrict__ ho_h, unsigned short* __restrict__ ho_l,
    int use_x) {
  __shared__ __align__(16) unsigned short A_lds[2][2][64][72];  // [buf][hi/lo][row][k64+8]
  __shared__ __align__(16) unsigned short W_lds[2][2][96][72];  // [buf][hi/lo][g*32+jr][k64+8]

  const int tid = threadIdx.x;
  const int bid = blockIdx.x;
  // XCD-affinity: bids == x (mod 8) land on XCD x; give XCD x jt in {4x..4x+3}
  const int xcd = bid & 7;
  const int q = bid >> 3;                 // 0..31
  const int jt = xcd * 4 + (q & 3);       // 0..31  h-col tile (32 cols)
  const int bt = q >> 2;                  // 0..7   batch tile (64 rows)

  const int wv = tid >> 6;                // wave 0..7
  const int wr = wv >> 1;                 // 16-row frag (0..3)
  const int wc = wv & 1;                  // 16-col half (0..1)
  const int lane = tid & 63;
  const int m = lane & 15;
  const int ko = (lane >> 4) << 3;        // 0,8,16,24 within 32-k chunk
  const int wj = wc * 16 + m;             // col within 32-col gate block

  f32x4 accR = {}, accZ = {}, accGin = {}, accGhn = {};
  us8 rg[5];  // staging: 2 A slots + 3 W slots per thread (2560 slots/phase)

  auto load_phase = [&](int p) {
    const unsigned short *Ah_s, *Al_s, *Wh_s, *Wl_s;
    int kb, ldA, ldW;
    if (p < 16) { Ah_s = h_h; Al_s = h_l; Wh_s = whh_h; Wl_s = whh_l; kb = p << 6; ldA = H_; ldW = H_; }
    else        { Ah_s = x_h; Al_s = x_l; Wh_s = wih_h; Wl_s = wih_l; kb = (p - 16) << 6; ldA = I_; ldW = I_; }
#pragma unroll
    for (int i = 0; i < 2; ++i) {  // A: 2hl x 64 rows x 8 ss = 1024 slots
      int t2 = i * 512 + tid;
      int hl2 = t2 >> 9, rem = t2 & 511;
      int rr = rem >> 3, ss = rem & 7;
      const unsigned short* s = hl2 ? Al_s : Ah_s;
      rg[i] = *(const us8*)&s[(bt * 64 + rr) * ldA + kb + ss * 8];
    }
#pragma unroll
    for (int i = 2; i < 5; ++i) {  // W: 2hl x 96 rows x 8 ss = 1536 slots
      int t2 = (i - 2) * 512 + tid;               // 0..1535
      int hl2 = (t2 >= 768) ? 1 : 0;
      int rem = t2 - 768 * hl2;                   // 0..767
      int row = rem >> 3, ss = rem & 7;           // row = g*32+jr
      int g = row >> 5, jr = row & 31;
      const unsigned short* s = hl2 ? Wl_s : Wh_s;
      rg[i] = *(const us8*)&s[(g * H_ + jt * 32 + jr) * ldW + kb + ss * 8];
    }
  };

  auto write_phase = [&](int nb) {
#pragma unroll
    for (int i = 0; i < 2; ++i) {
      int t2 = i * 512 + tid;
      int hl2 = t2 >> 9, rem = t2 & 511;
      int rr = rem >> 3, ss = rem & 7;
      *(us8*)&A_lds[nb][hl2][rr][ss * 8] = rg[i];
    }
#pragma unroll
    for (int i = 2; i < 5; ++i) {
      int t2 = (i - 2) * 512 + tid;
      int hl2 = (t2 >= 768) ? 1 : 0;
      int rem = t2 - 768 * hl2;
      int row = rem >> 3, ss = rem & 7;
      *(us8*)&W_lds[nb][hl2][row][ss * 8] = rg[i];
    }
  };

  auto compute_phase = [&](int cb, f32x4& accN) {
    __builtin_amdgcn_s_setprio(1);
#pragma unroll
    for (int kk = 0; kk < 64; kk += 32) {
      bf16x8 ah = *(const bf16x8*)&A_lds[cb][0][wr * 16 + m][kk + ko];
      bf16x8 al = *(const bf16x8*)&A_lds[cb][1][wr * 16 + m][kk + ko];
      bf16x8 wrh = *(const bf16x8*)&W_lds[cb][0][wj][kk + ko];
      bf16x8 wrl = *(const bf16x8*)&W_lds[cb][1][wj][kk + ko];
      bf16x8 wzh = *(const bf16x8*)&W_lds[cb][0][wj + 32][kk + ko];
      bf16x8 wzl = *(const bf16x8*)&W_lds[cb][1][wj + 32][kk + ko];
      bf16x8 wnh = *(const bf16x8*)&W_lds[cb][0][wj + 64][kk + ko];
      bf16x8 wnl = *(const bf16x8*)&W_lds[cb][1][wj + 64][kk + ko];
      MFMA(ah, wrh, accR); MFMA(ah, wrl, accR); MFMA(al, wrh, accR);
      MFMA(ah, wzh, accZ); MFMA(ah, wzl, accZ); MFMA(al, wzh, accZ);
      MFMA(ah, wnh, accN); MFMA(ah, wnl, accN); MFMA(al, wnh, accN);
    }
    __builtin_amdgcn_s_setprio(0);
  };

  // pipeline: compute phase p from buf p&1; write phase p+1 into buf (p+1)&1.
  load_phase(0);
  write_phase(0);
  load_phase(1);
  const int NP = use_x ? 20 : 16;
  for (int p = 0; p < NP; ++p) {
    __syncthreads();
    write_phase((p + 1) & 1);
    int pl = (p + 2 < NP) ? (p + 2) : (NP - 1);
    load_phase(pl);
    if (p < 16) compute_phase(p & 1, accGhn);
    else        compute_phase(p & 1, accGin);
  }

  // epilogue: gates + h_new.  D layout: col = lane&15, row = (lane>>4)*4 + reg.
  const int j = jt * 32 + wc * 16 + m;
  const float bir = b_ih[j],          bhr = b_hh[j];
  const float biz = b_ih[H_ + j],     bhz = b_hh[H_ + j];
  const float bin = b_ih[2 * H_ + j], bhn = b_hh[2 * H_ + j];
  const int r0 = (lane >> 4) << 2;
#pragma unroll
  for (int r2 = 0; r2 < 4; ++r2) {
    int b = bt * 64 + wr * 16 + r0 + r2;
    float gr = accR[r2] + bir + bhr;
    float gz = accZ[r2] + biz + bhz;
    float rr = 1.f / (1.f + __expf(-gr));
    float zz = 1.f / (1.f + __expf(-gz));
    float gn = accGin[r2] + bin + rr * (accGhn[r2] + bhn);
    float nn = tanhf(gn);
    float hold = bf2f(h_h[b * H_ + j]) + bf2f(h_l[b * H_ + j]);
    float hn = (1.f - zz) * nn + zz * hold;
    unsigned short hi = f2bf(hn);
    ho_h[b * H_ + j] = hi;
    ho_l[b * H_ + j] = f2bf(hn - bf2f(hi));
  }
}

// ---------------------------------------------------------------------------
// gru_head: y = h_new @ W_head^T + b_head.  Writes fp32 ys[t] and bf16 hi/lo x.
// 256 blocks: 32 b-tiles (16 rows) x 8 i-tiles (32 cols); 128 threads = 2 waves,
// wave w owns i-cols w*16..w*16+15.  K-step 128 -> 8 phases.  bid&7 = it (XCD).
// ---------------------------------------------------------------------------
__global__ __launch_bounds__(128) void gru_head(
    const unsigned short* __restrict__ hs_h, const unsigned short* __restrict__ hs_l,
    const unsigned short* __restrict__ whd_h, const unsigned short* __restrict__ whd_l,
    const float* __restrict__ b_head,
    float* __restrict__ out,
    unsigned short* __restrict__ xo_h, unsigned short* __restrict__ xo_l) {
  __shared__ __align__(16) unsigned short A_lds[2][2][16][136];  // [buf][hl][row][k128+8]
  __shared__ __align__(16) unsigned short W_lds[2][2][32][136];

  const int tid = threadIdx.x;
  const int bid = blockIdx.x;
  const int it = bid & 7;    // i tile, 32 cols  (maps to XCD bid%8)
  const int bt = bid >> 3;   // batch tile, 16 rows
  const int w = tid >> 6, lane = tid & 63, m = lane & 15;
  const int ko = (lane >> 4) << 3;

  f32x4 acc = {};
  us8 rg[12];

  auto load_ph = [&](int p) {
    int kb = p << 7;
#pragma unroll
    for (int i = 0; i < 4; ++i) {  // A: 2hl x 16 rows x 16 ss = 512 slots
      int t2 = i * 128 + tid;      // 0..511
      int hl2 = t2 >> 8, rem = t2 & 255;
      int rr = rem >> 4, ss = rem & 15;
      const unsigned short* s = hl2 ? hs_l : hs_h;
      rg[i] = *(const us8*)&s[(bt * 16 + rr) * H_ + kb + ss * 8];
    }
#pragma unroll
    for (int i = 4; i < 12; ++i) {  // W: 2hl x 32 rows x 16 ss = 1024 slots
      int t2 = (i - 4) * 128 + tid; // 0..1023
      int hl2 = t2 >> 9, rem = t2 & 511;
      int ir = rem >> 4, ss = rem & 15;
      const unsigned short* s = hl2 ? whd_l : whd_h;
      rg[i] = *(const us8*)&s[(it * 32 + ir) * H_ + kb + ss * 8];
    }
  };

  auto write_ph = [&](int nb) {
#pragma unroll
    for (int i = 0; i < 4; ++i) {
      int t2 = i * 128 + tid;
      int hl2 = t2 >> 8, rem = t2 & 255;
      int rr = rem >> 4, ss = rem & 15;
      *(us8*)&A_lds[nb][hl2][rr][ss * 8] = rg[i];
    }
#pragma unroll
    for (int i = 4; i < 12; ++i) {
      int t2 = (i - 4) * 128 + tid;
      int hl2 = t2 >> 9, rem = t2 & 511;
      int ir = rem >> 4, ss = rem & 15;
      *(us8*)&W_lds[nb][hl2][ir][ss * 8] = rg[i];
    }
  };

  auto comp = [&](int cb) {
    __builtin_amdgcn_s_setprio(1);
#pragma unroll
    for (int kk = 0; kk < 128; kk += 32) {
      bf16x8 ah = *(const bf16x8*)&A_lds[cb][0][m][kk + ko];
      bf16x8 al = *(const bf16x8*)&A_lds[cb][1][m][kk + ko];
      bf16x8 wh = *(const bf16x8*)&W_lds[cb][0][w * 16 + m][kk + ko];
      bf16x8 wl = *(const bf16x8*)&W_lds[cb][1][w * 16 + m][kk + ko];
      MFMA(ah, wh, acc); MFMA(ah, wl, acc); MFMA(al, wh, acc);
    }
    __builtin_amdgcn_s_setprio(0);
  };

  load_ph(0);
  write_ph(0);
  load_ph(1);
  const int NP = 8;
  for (int p = 0; p < NP; ++p) {
    __syncthreads();
    write_ph((p + 1) & 1);
    int pl = (p + 2 < NP) ? (p + 2) : (NP - 1);
    load_ph(pl);
    comp(p & 1);
  }

  const int i = it * 32 + w * 16 + m;
  const float bh = b_head[i];
  const int r0 = (lane >> 4) << 2;
#pragma unroll
  for (int r2 = 0; r2 < 4; ++r2) {
    int b = bt * 16 + r0 + r2;
    float y = acc[r2] + bh;
    out[b * I_ + i] = y;
    unsigned short hi = f2bf(y);
    xo_h[b * I_ + i] = hi;
    xo_l[b * I_ + i] = f2bf(y - bf2f(hi));
  }
}

// ---------------------------------------------------------------------------
extern "C" void kernel_launch(void* const* d_in, const int* in_sizes, int n_in,
                              void* d_out, int out_size, void* d_ws, size_t ws_size,
                              hipStream_t stream) {
  (void)in_sizes; (void)n_in; (void)out_size; (void)ws_size;
  const float* ctx    = (const float*)d_in[0];
  // d_in[1] = length (scalar, fixed 256)
  const float* W_ih   = (const float*)d_in[2];
  const float* W_hh   = (const float*)d_in[3];
  const float* b_ih   = (const float*)d_in[4];
  const float* b_hh   = (const float*)d_in[5];
  const float* W_head = (const float*)d_in[6];
  const float* b_head = (const float*)d_in[7];
  float* out = (float*)d_out;

  char* p = (char*)d_ws;
  unsigned short* whh_h = (unsigned short*)p; p += 6291456;
  unsigned short* whh_l = (unsigned short*)p; p += 6291456;
  unsigned short* wih_h = (unsigned short*)p; p += 1572864;
  unsigned short* wih_l = (unsigned short*)p; p += 1572864;
  unsigned short* whd_h = (unsigned short*)p; p += 524288;
  unsigned short* whd_l = (unsigned short*)p; p += 524288;
  unsigned short* hh[2]; unsigned short* hl[2];
  hh[0] = (unsigned short*)p; p += 1048576;
  hl[0] = (unsigned short*)p; p += 1048576;
  hh[1] = (unsigned short*)p; p += 1048576;
  hl[1] = (unsigned short*)p; p += 1048576;
  unsigned short* xh = (unsigned short*)p; p += 262144;
  unsigned short* xl = (unsigned short*)p; p += 262144;
  // total ws used: 21,495,808 bytes

  gru_prep<<<2048, 256, 0, stream>>>(W_hh, W_ih, W_head, ctx,
                                     whh_h, whh_l, wih_h, wih_l, whd_h, whd_l,
                                     hh[0], hl[0]);

  for (int t = 0; t < L_; ++t) {
    const int src = t & 1, dst = src ^ 1;
    gru_cell<<<256, 512, 0, stream>>>(hh[src], hl[src], xh, xl,
                                      whh_h, whh_l, wih_h, wih_l,
                                      b_ih, b_hh, hh[dst], hl[dst], t > 0 ? 1 : 0);
    gru_head<<<256, 128, 0, stream>>>(hh[dst], hl[dst], whd_h, whd_l, b_head,
                                      out + (size_t)t * B_ * I_, xh, xl);
  }
}